// Round 13
// baseline (211.685 us; speedup 1.0000x reference)
//
#include <hip/hip_runtime.h>
#include <hip/hip_bf16.h>

#define NEG_INF -9.0e15f

using u16 = unsigned short;

__device__ __forceinline__ float b2f(__hip_bfloat16 v) { return __bfloat162float(v); }
__device__ __forceinline__ float ldv(const float* p, int i) { return p[i]; }
__device__ __forceinline__ float ldv(const __hip_bfloat16* p, int i) { return __bfloat162float(p[i]); }

__device__ __forceinline__ void async16(const void* g, void* l) {
    __builtin_amdgcn_global_load_lds(
        (__attribute__((address_space(1))) void*)(g),
        (__attribute__((address_space(3))) void*)(l), 16, 0, 0);
}

// wave-level dtype sniff (uniform per wave): bf16 weights -> sane exponents.
__device__ __forceinline__ int sniff(const void* wnode) {
    const u16* w = (const u16*)wnode;
    int lane = threadIdx.x & 63;
    u16 u = w[2 * lane];
    int e = (u >> 7) & 0xFF;
    unsigned long long m = __ballot(e >= 100 && e <= 140);
    return __popcll(m) >= 48;
}

// ===========================================================================
// Round-13: round-12 base (XCD mapping blk = s*32+b, barrier-free attn) +
// (1) W-tile-0 prefetch hoisted to k_attn_gat ENTRY (cold-HBM fetch hides
//     under the whole attn phase instead of serializing after it),
// (2) 64-row W tiles in k_attn_gat's gat phase (4 barrier-drains, was 8),
// (3) deeper PV unroll. These target the serial-latency heads that per-
// dispatch counters can't see; bodies otherwise byte-identical to r12.
// ===========================================================================

// gat main loop + epilogue. TR = W-tile rows (32 or 64). Assumes xsT[k][r]
// (stride 10) is populated and (bf16) W tile 0 staged into Wbuf[pb0] and
// drained. Computes h rows row0..row0+7 and s1/s2.
template <int IS_BF, int TR>
__device__ __forceinline__ void gat_core(
    char* smem, int t, int row0, int pb0,
    const void* __restrict__ gat_W, const void* __restrict__ gat_a, int l,
    float* __restrict__ hw, float* __restrict__ s1w, float* __restrict__ s2w) {
    float* xsT = (float*)smem;
    const int tx = t & 63, w = t >> 6;
    const int c0 = 4 * tx;
    float acc0[4], acc1[4];
    #pragma unroll
    for (int j = 0; j < 4; ++j) { acc0[j] = 0.f; acc1[j] = 0.f; }

    if (IS_BF) {
        u16* Wb0 = (u16*)(smem + 10240);
        const u16* Wl = (const u16*)gat_W + (size_t)l * 65536;
        auto stage_rows = [&](int r0, int buf) {
            const char* g = (const char*)Wl + (size_t)r0 * 512;
            char* lp = (char*)(Wb0 + buf * (TR * 256));
            for (int off = t * 16; off < TR * 512; off += 4096)
                async16(g + off, lp + off);
        };
        int pb = pb0;
        const int NPH = 256 / TR;
        for (int tt = 0; tt < NPH; ++tt) {
            if (tt < NPH - 1) stage_rows(TR * (tt + 1), pb ^ 1);
            const u16* Wp = Wb0 + pb * (TR * 256);
            const int k0 = TR * tt;
            #pragma unroll 8
            for (int kk = 0; kk < TR; ++kk) {
                uint2 wv = *(const uint2*)(Wp + kk * 256 + c0);
                float w0 = __uint_as_float(wv.x << 16);
                float w1 = __uint_as_float(wv.x & 0xffff0000u);
                float w2 = __uint_as_float(wv.y << 16);
                float w3 = __uint_as_float(wv.y & 0xffff0000u);
                float2 xp = *(const float2*)&xsT[(k0 + kk) * 10 + 2 * w];
                acc0[0] += xp.x * w0; acc0[1] += xp.x * w1;
                acc0[2] += xp.x * w2; acc0[3] += xp.x * w3;
                acc1[0] += xp.y * w0; acc1[1] += xp.y * w1;
                acc1[2] += xp.y * w2; acc1[3] += xp.y * w3;
            }
            __syncthreads();
            pb ^= 1;
        }
        const __hip_bfloat16* ga = (const __hip_bfloat16*)gat_a + (size_t)l * 512;
        float d10 = 0.f, d20 = 0.f, d11 = 0.f, d21 = 0.f;
        #pragma unroll
        for (int j = 0; j < 4; ++j) {
            float a1v = b2f(ga[c0 + j]), a2v = b2f(ga[256 + c0 + j]);
            d10 += acc0[j] * a1v; d20 += acc0[j] * a2v;
            d11 += acc1[j] * a1v; d21 += acc1[j] * a2v;
        }
        #pragma unroll
        for (int off = 1; off < 64; off <<= 1) {
            d10 += __shfl_xor(d10, off, 64); d20 += __shfl_xor(d20, off, 64);
            d11 += __shfl_xor(d11, off, 64); d21 += __shfl_xor(d21, off, 64);
        }
        if (tx == 0) {
            s1w[row0 + 2 * w] = d10;     s2w[row0 + 2 * w] = d20;
            s1w[row0 + 2 * w + 1] = d11; s2w[row0 + 2 * w + 1] = d21;
        }
        *(float4*)&hw[(size_t)(row0 + 2 * w) * 256 + c0]     = (float4){acc0[0], acc0[1], acc0[2], acc0[3]};
        *(float4*)&hw[(size_t)(row0 + 2 * w + 1) * 256 + c0] = (float4){acc1[0], acc1[1], acc1[2], acc1[3]};
    } else {
        const float* Wlf = (const float*)gat_W + (size_t)l * 65536;
        const float* gaf = (const float*)gat_a + (size_t)l * 512;
        #pragma unroll 4
        for (int k = 0; k < 256; ++k) {
            float4 wf = *(const float4*)(Wlf + k * 256 + c0);
            float2 xp = *(const float2*)&xsT[k * 10 + 2 * w];
            acc0[0] += xp.x * wf.x; acc0[1] += xp.x * wf.y;
            acc0[2] += xp.x * wf.z; acc0[3] += xp.x * wf.w;
            acc1[0] += xp.y * wf.x; acc1[1] += xp.y * wf.y;
            acc1[2] += xp.y * wf.z; acc1[3] += xp.y * wf.w;
        }
        float d10 = 0.f, d20 = 0.f, d11 = 0.f, d21 = 0.f;
        #pragma unroll
        for (int j = 0; j < 4; ++j) {
            float a1v = gaf[c0 + j], a2v = gaf[256 + c0 + j];
            d10 += acc0[j] * a1v; d20 += acc0[j] * a2v;
            d11 += acc1[j] * a1v; d21 += acc1[j] * a2v;
        }
        #pragma unroll
        for (int off = 1; off < 64; off <<= 1) {
            d10 += __shfl_xor(d10, off, 64); d20 += __shfl_xor(d20, off, 64);
            d11 += __shfl_xor(d11, off, 64); d21 += __shfl_xor(d21, off, 64);
        }
        if (tx == 0) {
            s1w[row0 + 2 * w] = d10;     s2w[row0 + 2 * w] = d20;
            s1w[row0 + 2 * w + 1] = d11; s2w[row0 + 2 * w + 1] = d21;
        }
        *(float4*)&hw[(size_t)(row0 + 2 * w) * 256 + c0]     = (float4){acc0[0], acc0[1], acc0[2], acc0[3]};
        *(float4*)&hw[(size_t)(row0 + 2 * w + 1) * 256 + c0] = (float4){acc1[0], acc1[1], acc1[2], acc1[3]};
    }
}

// Barrier-free attention (round-12 proven): softmax(mask(leaky(s1+s2))) @ h
// -> ac0/ac1 (rows 2w,2w+1; cols 4tx..4tx+3). att in registers; PV broadcasts
// via __shfl (wave-uniform j); h read directly from home-XCD L2.
__device__ __forceinline__ void attn_reg(
    int t, int b, int s,
    const float* __restrict__ hw, const float* __restrict__ s1w,
    const float* __restrict__ s2w, const int* __restrict__ adj,
    float ac0[4], float ac1[4]) {
    const int w = t >> 6, lane = t & 63;
    const int i0 = s << 3;
    const int ir0 = i0 + 2 * w, ir1 = ir0 + 1;
    const int* a0 = adj + (size_t)(b * 128 + ir0) * 128;
    const int* a1 = adj + (size_t)(b * 128 + ir1) * 128;
    int m00 = a0[lane], m01 = a0[lane + 64], m10 = a1[lane], m11 = a1[lane + 64];
    float sv0 = s1w[b * 128 + ir0], sv1 = s1w[b * 128 + ir1];
    float t0 = s2w[b * 128 + lane], t1 = s2w[b * 128 + lane + 64];
    float e00 = sv0 + t0; e00 = (e00 >= 0.f) ? e00 : 0.2f * e00;
    float e01 = sv0 + t1; e01 = (e01 >= 0.f) ? e01 : 0.2f * e01;
    float e10 = sv1 + t0; e10 = (e10 >= 0.f) ? e10 : 0.2f * e10;
    float e11 = sv1 + t1; e11 = (e11 >= 0.f) ? e11 : 0.2f * e11;
    float v00 = (m00 > 0) ? e00 : NEG_INF;
    float v01 = (m01 > 0) ? e01 : NEG_INF;
    float v10 = (m10 > 0) ? e10 : NEG_INF;
    float v11 = (m11 > 0) ? e11 : NEG_INF;
    float mx0 = fmaxf(v00, v01), mx1 = fmaxf(v10, v11);
    #pragma unroll
    for (int off = 1; off < 64; off <<= 1) {
        mx0 = fmaxf(mx0, __shfl_xor(mx0, off, 64));
        mx1 = fmaxf(mx1, __shfl_xor(mx1, off, 64));
    }
    float p00 = __expf(v00 - mx0), p01 = __expf(v01 - mx0);
    float p10 = __expf(v10 - mx1), p11 = __expf(v11 - mx1);
    float sm0 = p00 + p01, sm1 = p10 + p11;
    #pragma unroll
    for (int off = 1; off < 64; off <<= 1) {
        sm0 += __shfl_xor(sm0, off, 64);
        sm1 += __shfl_xor(sm1, off, 64);
    }
    float inv0 = 1.0f / sm0, inv1 = 1.0f / sm1;
    float p00s = p00 * inv0, p01s = p01 * inv0;
    float p10s = p10 * inv1, p11s = p11 * inv1;

    const float* hb = hw + (size_t)b * 32768;
    const int c0 = 4 * (t & 63);
    ac0[0] = 0.f; ac0[1] = 0.f; ac0[2] = 0.f; ac0[3] = 0.f;
    ac1[0] = 0.f; ac1[1] = 0.f; ac1[2] = 0.f; ac1[3] = 0.f;
    #pragma unroll 16
    for (int j = 0; j < 64; ++j) {
        float a0v = __shfl(p00s, j, 64);
        float a1v = __shfl(p10s, j, 64);
        float4 hv = *(const float4*)&hb[(size_t)j * 256 + c0];
        ac0[0] += a0v * hv.x; ac0[1] += a0v * hv.y;
        ac0[2] += a0v * hv.z; ac0[3] += a0v * hv.w;
        ac1[0] += a1v * hv.x; ac1[1] += a1v * hv.y;
        ac1[2] += a1v * hv.z; ac1[3] += a1v * hv.w;
    }
    #pragma unroll 16
    for (int j = 0; j < 64; ++j) {
        float a0v = __shfl(p01s, j, 64);
        float a1v = __shfl(p11s, j, 64);
        float4 hv = *(const float4*)&hb[(size_t)(j + 64) * 256 + c0];
        ac0[0] += a0v * hv.x; ac0[1] += a0v * hv.y;
        ac0[2] += a0v * hv.z; ac0[3] += a0v * hv.w;
        ac1[0] += a1v * hv.x; ac1[1] += a1v * hv.y;
        ac1[2] += a1v * hv.z; ac1[3] += a1v * hv.w;
    }
}

// ===========================================================================
// K1: gat layer 0 (nf@Wn+b projection prologue, 32-row tiles, proven).
// blk = s*32 + b mapping (XCD-home = b%8).
// ===========================================================================
__global__ __launch_bounds__(256) void k_gat_first(
    const void* __restrict__ nf, const void* __restrict__ Wn_raw,
    const void* __restrict__ bn,
    const void* __restrict__ gat_W, const void* __restrict__ gat_a,
    float* __restrict__ hw, float* __restrict__ s1w, float* __restrict__ s2w) {
    __shared__ __align__(16) char smem[43008];
    const int t = threadIdx.x;
    const int blk = blockIdx.x;
    const int b = blk & 31, s = blk >> 5;
    const int row0 = b * 128 + s * 8;
    const int tx = t & 63, w = t >> 6;
    const int c0 = 4 * tx;
    float* xsT = (float*)smem;
    float acc0[4], acc1[4];

    if (sniff(Wn_raw)) {
        u16* Wb0 = (u16*)(smem + 10240);
        const u16* Wl = (const u16*)gat_W;   // layer 0
        auto stage = [&](const u16* src, int r0, int nr, int buf) {
            const char* g = (const char*)src + (size_t)r0 * 512;
            char* lp = (char*)(Wb0 + buf * 8192);
            int bytes = nr * 512;
            for (int off = t * 16; off < bytes; off += 4096)
                async16(g + off, lp + off);
        };
        auto tile = [&](int buf, int k0, int nr) {
            const u16* Wp = Wb0 + buf * 8192;
            #pragma unroll 8
            for (int kk = 0; kk < nr; ++kk) {
                uint2 wv = *(const uint2*)(Wp + kk * 256 + c0);
                float w0 = __uint_as_float(wv.x << 16);
                float w1 = __uint_as_float(wv.x & 0xffff0000u);
                float w2 = __uint_as_float(wv.y << 16);
                float w3 = __uint_as_float(wv.y & 0xffff0000u);
                float2 xp = *(const float2*)&xsT[(k0 + kk) * 10 + 2 * w];
                acc0[0] += xp.x * w0; acc0[1] += xp.x * w1;
                acc0[2] += xp.x * w2; acc0[3] += xp.x * w3;
                acc1[0] += xp.y * w0; acc1[1] += xp.y * w1;
                acc1[2] += xp.y * w2; acc1[3] += xp.y * w3;
            }
        };
        const u16* Wnl = (const u16*)Wn_raw;
        stage(Wnl, 0, 32, 0);
        const u16* nfu = (const u16*)nf;
        for (int i = t; i < 624; i += 256) {
            int r = i / 78, k = i - r * 78;
            xsT[k * 10 + r] = __uint_as_float(((unsigned)nfu[(row0 + r) * 78 + k]) << 16);
        }
        const __hip_bfloat16* bnb = (const __hip_bfloat16*)bn;
        #pragma unroll
        for (int j = 0; j < 4; ++j) { acc0[j] = b2f(bnb[c0 + j]); acc1[j] = acc0[j]; }
        __syncthreads();
        stage(Wnl, 32, 32, 1);
        tile(0, 0, 32);
        __syncthreads();
        stage(Wnl, 64, 14, 0);
        tile(1, 32, 32);
        __syncthreads();
        stage(Wl, 0, 32, 1);      // first main-W tile under last Wn tile
        tile(0, 64, 14);
        __syncthreads();
        #pragma unroll
        for (int j = 0; j < 4; ++j) {
            xsT[(c0 + j) * 10 + 2 * w]     = acc0[j];
            xsT[(c0 + j) * 10 + 2 * w + 1] = acc1[j];
        }
        __syncthreads();          // xsT ready; Wl tile0 drained, in buf1
        gat_core<1, 32>(smem, t, row0, /*pb0=*/1, gat_W, gat_a, 0, hw, s1w, s2w);
    } else {
        const float* nff = (const float*)nf;
        for (int i = t; i < 624; i += 256) {
            int r = i / 78, k = i - r * 78;
            xsT[k * 10 + r] = nff[(row0 + r) * 78 + k];
        }
        __syncthreads();
        const float* Wnf = (const float*)Wn_raw;
        const float* bnf = (const float*)bn;
        #pragma unroll
        for (int j = 0; j < 4; ++j) { acc0[j] = bnf[c0 + j]; acc1[j] = acc0[j]; }
        for (int k = 0; k < 78; ++k) {
            float4 wf = *(const float4*)(Wnf + k * 256 + c0);
            float2 xp = *(const float2*)&xsT[k * 10 + 2 * w];
            acc0[0] += xp.x * wf.x; acc0[1] += xp.x * wf.y;
            acc0[2] += xp.x * wf.z; acc0[3] += xp.x * wf.w;
            acc1[0] += xp.y * wf.x; acc1[1] += xp.y * wf.y;
            acc1[2] += xp.y * wf.z; acc1[3] += xp.y * wf.w;
        }
        __syncthreads();
        #pragma unroll
        for (int j = 0; j < 4; ++j) {
            xsT[(c0 + j) * 10 + 2 * w]     = acc0[j];
            xsT[(c0 + j) * 10 + 2 * w + 1] = acc1[j];
        }
        __syncthreads();
        gat_core<0, 32>(smem, t, row0, 0, gat_W, gat_a, 0, hw, s1w, s2w);
    }
}

// ===========================================================================
// K2/K3: barrier-free attn layer l-1 + gat layer l (64-row W tiles).
// W tile-0 prefetch issued at kernel ENTRY so its cold-HBM latency hides
// under the whole attn phase. blk = s*32 + b.
// ===========================================================================
__global__ __launch_bounds__(256) void k_attn_gat(
    const float* __restrict__ h_in, const float* __restrict__ s1_in,
    const float* __restrict__ s2_in, const int* __restrict__ adj,
    const void* __restrict__ gat_W, const void* __restrict__ gat_a, int l,
    const void* __restrict__ Wn_raw,
    float* __restrict__ h_out, float* __restrict__ s1_out, float* __restrict__ s2_out) {
    __shared__ __align__(16) char smem[75776];   // 10240 xsT + 2 x 32768 W
    const int t = threadIdx.x;
    const int blk = blockIdx.x;
    const int b = blk & 31, s = blk >> 5;
    const int row0 = b * 128 + s * 8;
    const int isbf = sniff(Wn_raw);

    if (isbf) {
        // entry prefetch: W rows 0..63 -> buf0; drains at the barrier below,
        // fully hidden under attn_reg (~30 µs of independent work).
        u16* Wb0 = (u16*)(smem + 10240);
        const u16* Wl = (const u16*)gat_W + (size_t)l * 65536;
        for (int off = t * 16; off < 32768; off += 4096)
            async16((const char*)Wl + off, (char*)Wb0 + off);
    }

    float ac0[4], ac1[4];
    attn_reg(t, b, s, h_in, s1_in, s2_in, adj, ac0, ac1);

    const int tx = t & 63, w = t >> 6;
    const int c0 = 4 * tx;
    float* xsT = (float*)smem;
    #pragma unroll
    for (int j = 0; j < 4; ++j) {
        xsT[(c0 + j) * 10 + 2 * w]     = fmaxf(ac0[j], 0.f);
        xsT[(c0 + j) * 10 + 2 * w + 1] = fmaxf(ac1[j], 0.f);
    }
    __syncthreads();   // xsT visible + (bf16) W tile0 drained into buf0
    if (isbf)
        gat_core<1, 64>(smem, t, row0, /*pb0=*/0, gat_W, gat_a, l, h_out, s1_out, s2_out);
    else
        gat_core<0, 64>(smem, t, row0, 0, gat_W, gat_a, l, h_out, s1_out, s2_out);
}

// ===========================================================================
// K4: barrier-free attn layer 2 + mean-pool partials, blk = s*32 + b.
// ===========================================================================
__global__ __launch_bounds__(256) void k_attn_pool(
    const float* __restrict__ h_in, const float* __restrict__ s1_in,
    const float* __restrict__ s2_in, const int* __restrict__ adj,
    float* __restrict__ gpart) {
    __shared__ __align__(16) float pool_red[4][256];
    const int t = threadIdx.x;
    const int blk = blockIdx.x;
    const int b = blk & 31, s = blk >> 5;
    float ac0[4], ac1[4];
    attn_reg(t, b, s, h_in, s1_in, s2_in, adj, ac0, ac1);
    const int tx = t & 63, ty = t >> 6;
    float4 pr = {(fmaxf(ac0[0],0.f) + fmaxf(ac1[0],0.f)) * (1.f/128.f),
                 (fmaxf(ac0[1],0.f) + fmaxf(ac1[1],0.f)) * (1.f/128.f),
                 (fmaxf(ac0[2],0.f) + fmaxf(ac1[2],0.f)) * (1.f/128.f),
                 (fmaxf(ac0[3],0.f) + fmaxf(ac1[3],0.f)) * (1.f/128.f)};
    *(float4*)&pool_red[ty][4 * tx] = pr;
    __syncthreads();
    if (t < 64) {
        float4 r0 = ((const float4*)&pool_red[0][0])[t];
        float4 r1 = ((const float4*)&pool_red[1][0])[t];
        float4 r2 = ((const float4*)&pool_red[2][0])[t];
        float4 r3 = ((const float4*)&pool_red[3][0])[t];
        float4 o = {r0.x+r1.x+r2.x+r3.x, r0.y+r1.y+r2.y+r3.y,
                    r0.z+r1.z+r2.z+r3.z, r0.w+r1.w+r2.w+r3.w};
        *(float4*)&gpart[((size_t)b * 16 + s) * 256 + 4 * t] = o;
    }
}

// ===========================================================================
// K5: head — pool MLPs + concat + out MLP (round-1 proven body)
// ===========================================================================
template <typename T>
__device__ __forceinline__ void head_body(
    int b, int t, const float* __restrict__ gpart,
    const T* scaf, const T* W_sc, const T* b_sc,
    const T* gp_w1, const T* gp_b1, const T* gp_w2, const T* gp_b2,
    const T* out_w1, const T* out_b1, const T* out_w2, const T* out_b2,
    float* gin_s, float* sproj, float* scaf_s,
    float* red1, float* red2, float* z1g, float* z1s,
    float* cvec, float* hdn, float* outv) {
    float g = 0.f;
    #pragma unroll
    for (int gg = 0; gg < 16; ++gg) g += gpart[((size_t)b * 16 + gg) * 256 + t];
    gin_s[t] = g;
    if (t < 20) scaf_s[t] = ldv(scaf, b * 20 + t);
    __syncthreads();
    {
        float sa = ldv(b_sc, t);
        #pragma unroll
        for (int k = 0; k < 20; ++k) sa += scaf_s[k] * ldv(W_sc, k * 256 + t);
        sproj[t] = sa;
    }
    __syncthreads();
    {
        int j = t & 127, khalf = t >> 7;
        int k0 = khalf * 128;
        float a1 = 0.f, a2 = 0.f;
        #pragma unroll 16
        for (int kk = 0; kk < 128; ++kk) {
            int k = k0 + kk;
            float wv = ldv(gp_w1, k * 128 + j);
            a1 += gin_s[k] * wv;
            a2 += sproj[k] * wv;
        }
        red1[t] = a1; red2[t] = a2;
    }
    __syncthreads();
    if (t < 128) {
        float bb = ldv(gp_b1, t);
        z1g[t] = fmaxf(bb + red1[t] + red1[t + 128], 0.f);
        z1s[t] = fmaxf(bb + red2[t] + red2[t + 128], 0.f);
    }
    __syncthreads();
    {
        int j = t & 63, q = t >> 6;
        int k0 = q * 32;
        float a1 = 0.f, a2 = 0.f;
        #pragma unroll
        for (int kk = 0; kk < 32; ++kk) {
            int k = k0 + kk;
            float wv = ldv(gp_w2, k * 64 + j);
            a1 += z1g[k] * wv;
            a2 += z1s[k] * wv;
        }
        red1[t] = a1; red2[t] = a2;
    }
    __syncthreads();
    if (t < 64) {
        float bb = ldv(gp_b2, t);
        cvec[t]      = fmaxf(bb + red1[t] + red1[t + 64] + red1[t + 128] + red1[t + 192], 0.f);
        cvec[64 + t] = fmaxf(bb + red2[t] + red2[t + 64] + red2[t + 128] + red2[t + 192], 0.f);
    }
    __syncthreads();
    {
        int j = t & 127, khalf = t >> 7;
        int k0 = khalf * 64;
        float a = 0.f;
        #pragma unroll 16
        for (int kk = 0; kk < 64; ++kk) {
            int k = k0 + kk;
            a += cvec[k] * ldv(out_w1, k * 128 + j);
        }
        red1[t] = a;
    }
    __syncthreads();
    if (t < 128) hdn[t] = fmaxf(ldv(out_b1, t) + red1[t] + red1[t + 128], 0.f);
    __syncthreads();
    if (t < 13) {
        float a = ldv(out_b2, t);
        #pragma unroll 16
        for (int k = 0; k < 128; ++k) a += hdn[k] * ldv(out_w2, k * 13 + t);
        outv[t] = a;
    }
}

__global__ __launch_bounds__(256) void k_head(
    const float* __restrict__ gpart, const void* __restrict__ scaf,
    const void* __restrict__ W_sc, const void* __restrict__ b_sc,
    const void* __restrict__ gp_w1, const void* __restrict__ gp_b1,
    const void* __restrict__ gp_w2, const void* __restrict__ gp_b2,
    const void* __restrict__ out_w1, const void* __restrict__ out_b1,
    const void* __restrict__ out_w2, const void* __restrict__ out_b2,
    void* __restrict__ out, const void* __restrict__ Wn) {
    int isbf = sniff(Wn);
    int b = blockIdx.x;
    int t = threadIdx.x;
    __shared__ float gin_s[256], sproj[256], scaf_s[20];
    __shared__ float red1[256], red2[256];
    __shared__ float z1g[128], z1s[128], cvec[128], hdn[128], outv[13];
    if (isbf) {
        head_body<__hip_bfloat16>(b, t, gpart,
            (const __hip_bfloat16*)scaf, (const __hip_bfloat16*)W_sc, (const __hip_bfloat16*)b_sc,
            (const __hip_bfloat16*)gp_w1, (const __hip_bfloat16*)gp_b1,
            (const __hip_bfloat16*)gp_w2, (const __hip_bfloat16*)gp_b2,
            (const __hip_bfloat16*)out_w1, (const __hip_bfloat16*)out_b1,
            (const __hip_bfloat16*)out_w2, (const __hip_bfloat16*)out_b2,
            gin_s, sproj, scaf_s, red1, red2, z1g, z1s, cvec, hdn, outv);
    } else {
        head_body<float>(b, t, gpart,
            (const float*)scaf, (const float*)W_sc, (const float*)b_sc,
            (const float*)gp_w1, (const float*)gp_b1,
            (const float*)gp_w2, (const float*)gp_b2,
            (const float*)out_w1, (const float*)out_b1,
            (const float*)out_w2, (const float*)out_b2,
            gin_s, sproj, scaf_s, red1, red2, z1g, z1s, cvec, hdn, outv);
    }
    __syncthreads();
    if (t < 13) {
        if (isbf) ((__hip_bfloat16*)out)[b * 13 + t] = __float2bfloat16(outv[t]);
        else      ((float*)out)[b * 13 + t] = outv[t];
    }
}

extern "C" void kernel_launch(void* const* d_in, const int* in_sizes, int n_in,
                              void* d_out, int out_size, void* d_ws, size_t ws_size,
                              hipStream_t stream) {
    (void)in_sizes; (void)n_in; (void)out_size; (void)ws_size;
    const void* nf     = d_in[0];
    const int*  adj    = (const int*)d_in[2];
    const void* scaf   = d_in[3];
    const void* W_node = d_in[4];
    const void* b_node = d_in[5];
    const void* gat_W  = d_in[6];
    const void* gat_a  = d_in[7];
    const void* W_sc   = d_in[8];
    const void* b_sc   = d_in[9];
    const void* gp_w1  = d_in[10];
    const void* gp_b1  = d_in[11];
    const void* gp_w2  = d_in[12];
    const void* gp_b2  = d_in[13];
    const void* out_w1 = d_in[14];
    const void* out_b1 = d_in[15];
    const void* out_w2 = d_in[16];
    const void* out_b2 = d_in[17];

    float* ws    = (float*)d_ws;
    float* hA    = ws;                      // 1,048,576 f32
    float* hB    = ws + 1048576;            // 1,048,576 f32
    float* s1A   = ws + 2097152;            // 4096
    float* s2A   = ws + 2101248;            // 4096
    float* s1B   = ws + 2105344;            // 4096
    float* s2B   = ws + 2109440;            // 4096
    float* gpart = ws + 2113536;            // 131,072

    // K1: gat layer 0
    k_gat_first<<<512, 256, 0, stream>>>(nf, W_node, b_node, gat_W, gat_a,
                                         hA, s1A, s2A);
    // K2: attn0 + gat1 (block-local x handoff, entry W prefetch)
    k_attn_gat<<<512, 256, 0, stream>>>(hA, s1A, s2A, adj, gat_W, gat_a, 1,
                                        W_node, hB, s1B, s2B);
    // K3: attn1 + gat2
    k_attn_gat<<<512, 256, 0, stream>>>(hB, s1B, s2B, adj, gat_W, gat_a, 2,
                                        W_node, hA, s1A, s2A);
    // K4: attn2 + pool
    k_attn_pool<<<512, 256, 0, stream>>>(hA, s1A, s2A, adj, gpart);
    // K5: head
    k_head<<<32, 256, 0, stream>>>(gpart, scaf, W_sc, b_sc, gp_w1, gp_b1, gp_w2, gp_b2,
                                   out_w1, out_b1, out_w2, out_b2, d_out, W_node);
}

// Round 14
// 203.087 us; speedup vs baseline: 1.0423x; 1.0423x over previous
//
#include <hip/hip_runtime.h>
#include <hip/hip_bf16.h>

#define NEG_INF -9.0e15f

using u16 = unsigned short;

__device__ __forceinline__ float b2f(__hip_bfloat16 v) { return __bfloat162float(v); }
__device__ __forceinline__ float ldv(const float* p, int i) { return p[i]; }
__device__ __forceinline__ float ldv(const __hip_bfloat16* p, int i) { return __bfloat162float(p[i]); }

__device__ __forceinline__ void async16(const void* g, void* l) {
    __builtin_amdgcn_global_load_lds(
        (__attribute__((address_space(1))) void*)(g),
        (__attribute__((address_space(3))) void*)(l), 16, 0, 0);
}

// wave-level dtype sniff (uniform per wave): bf16 weights -> sane exponents.
__device__ __forceinline__ int sniff(const void* wnode) {
    const u16* w = (const u16*)wnode;
    int lane = threadIdx.x & 63;
    u16 u = w[2 * lane];
    int e = (u >> 7) & 0xFF;
    unsigned long long m = __ballot(e >= 100 && e <= 140);
    return __popcll(m) >= 48;
}

// ===========================================================================
// FINAL (round-9 best-measured config, 206.87 µs): 5 kernels, block-local
// attn->gat fusion (x never materialized), kernel boundaries as the only
// cross-block sync. Session evidence (rounds 1-13): per-dispatch wall of
// ~42-46 µs is invariant to staging strategy, occupancy (x2), cache locality
// (FETCH /4.4), barrier count, and LDS usage, with VALUBusy pinned at
// 11-14% and no PMC resource saturated -> environmental per-dispatch floor;
// dispatch count (5) is the dataflow minimum, since every in-kernel
// cross-block sync primitive measured 70-400 µs (rounds 4-7).
// ===========================================================================

// gat main loop + epilogue. Assumes xsT[k][r] (stride 10) is populated and
// (for bf16) W tile 0 is staged into Wbuf[pb0] and drained (caller issued a
// __syncthreads() after stage). Computes h rows row0..row0+7 and s1/s2.
template <int IS_BF>
__device__ __forceinline__ void gat_core(
    char* smem, int t, int row0, int pb0,
    const void* __restrict__ gat_W, const void* __restrict__ gat_a, int l,
    float* __restrict__ hw, float* __restrict__ s1w, float* __restrict__ s2w) {
    float* xsT = (float*)smem;
    const int tx = t & 63, w = t >> 6;
    const int c0 = 4 * tx;
    float acc0[4], acc1[4];
    #pragma unroll
    for (int j = 0; j < 4; ++j) { acc0[j] = 0.f; acc1[j] = 0.f; }

    if (IS_BF) {
        u16* Wb0 = (u16*)(smem + 10240);
        const u16* Wl = (const u16*)gat_W + (size_t)l * 65536;
        auto stage_rows = [&](int r0, int nr, int buf) {
            const char* g = (const char*)Wl + (size_t)r0 * 512;
            char* lp = (char*)(Wb0 + buf * 8192);
            int bytes = nr * 512;
            for (int off = t * 16; off < bytes; off += 4096)
                async16(g + off, lp + off);
        };
        int pb = pb0;
        for (int tt = 0; tt < 8; ++tt) {
            if (tt < 7) stage_rows(32 * (tt + 1), 32, pb ^ 1);
            const u16* Wp = Wb0 + pb * 8192;
            const int k0 = 32 * tt;
            #pragma unroll 8
            for (int kk = 0; kk < 32; ++kk) {
                uint2 wv = *(const uint2*)(Wp + kk * 256 + c0);
                float w0 = __uint_as_float(wv.x << 16);
                float w1 = __uint_as_float(wv.x & 0xffff0000u);
                float w2 = __uint_as_float(wv.y << 16);
                float w3 = __uint_as_float(wv.y & 0xffff0000u);
                float2 xp = *(const float2*)&xsT[(k0 + kk) * 10 + 2 * w];
                acc0[0] += xp.x * w0; acc0[1] += xp.x * w1;
                acc0[2] += xp.x * w2; acc0[3] += xp.x * w3;
                acc1[0] += xp.y * w0; acc1[1] += xp.y * w1;
                acc1[2] += xp.y * w2; acc1[3] += xp.y * w3;
            }
            __syncthreads();
            pb ^= 1;
        }
        const __hip_bfloat16* ga = (const __hip_bfloat16*)gat_a + (size_t)l * 512;
        float d10 = 0.f, d20 = 0.f, d11 = 0.f, d21 = 0.f;
        #pragma unroll
        for (int j = 0; j < 4; ++j) {
            float a1v = b2f(ga[c0 + j]), a2v = b2f(ga[256 + c0 + j]);
            d10 += acc0[j] * a1v; d20 += acc0[j] * a2v;
            d11 += acc1[j] * a1v; d21 += acc1[j] * a2v;
        }
        #pragma unroll
        for (int off = 1; off < 64; off <<= 1) {
            d10 += __shfl_xor(d10, off, 64); d20 += __shfl_xor(d20, off, 64);
            d11 += __shfl_xor(d11, off, 64); d21 += __shfl_xor(d21, off, 64);
        }
        if (tx == 0) {
            s1w[row0 + 2 * w] = d10;     s2w[row0 + 2 * w] = d20;
            s1w[row0 + 2 * w + 1] = d11; s2w[row0 + 2 * w + 1] = d21;
        }
        *(float4*)&hw[(size_t)(row0 + 2 * w) * 256 + c0]     = (float4){acc0[0], acc0[1], acc0[2], acc0[3]};
        *(float4*)&hw[(size_t)(row0 + 2 * w + 1) * 256 + c0] = (float4){acc1[0], acc1[1], acc1[2], acc1[3]};
    } else {
        const float* Wlf = (const float*)gat_W + (size_t)l * 65536;
        const float* gaf = (const float*)gat_a + (size_t)l * 512;
        #pragma unroll 4
        for (int k = 0; k < 256; ++k) {
            float4 wf = *(const float4*)(Wlf + k * 256 + c0);
            float2 xp = *(const float2*)&xsT[k * 10 + 2 * w];
            acc0[0] += xp.x * wf.x; acc0[1] += xp.x * wf.y;
            acc0[2] += xp.x * wf.z; acc0[3] += xp.x * wf.w;
            acc1[0] += xp.y * wf.x; acc1[1] += xp.y * wf.y;
            acc1[2] += xp.y * wf.z; acc1[3] += xp.y * wf.w;
        }
        float d10 = 0.f, d20 = 0.f, d11 = 0.f, d21 = 0.f;
        #pragma unroll
        for (int j = 0; j < 4; ++j) {
            float a1v = gaf[c0 + j], a2v = gaf[256 + c0 + j];
            d10 += acc0[j] * a1v; d20 += acc0[j] * a2v;
            d11 += acc1[j] * a1v; d21 += acc1[j] * a2v;
        }
        #pragma unroll
        for (int off = 1; off < 64; off <<= 1) {
            d10 += __shfl_xor(d10, off, 64); d20 += __shfl_xor(d20, off, 64);
            d11 += __shfl_xor(d11, off, 64); d21 += __shfl_xor(d21, off, 64);
        }
        if (tx == 0) {
            s1w[row0 + 2 * w] = d10;     s2w[row0 + 2 * w] = d20;
            s1w[row0 + 2 * w + 1] = d11; s2w[row0 + 2 * w + 1] = d21;
        }
        *(float4*)&hw[(size_t)(row0 + 2 * w) * 256 + c0]     = (float4){acc0[0], acc0[1], acc0[2], acc0[3]};
        *(float4*)&hw[(size_t)(row0 + 2 * w + 1) * 256 + c0] = (float4){acc1[0], acc1[1], acc1[2], acc1[3]};
    }
}

// attn compute (round-1 proven): softmax(mask(leaky(s1+s2))) @ h -> ac0/ac1.
// Ends after the c-loop's final __syncthreads(); LDS is then reusable.
__device__ __forceinline__ void attn_compute(
    char* smem, int t, int b, int s,
    const float* __restrict__ hw, const float* __restrict__ s1w,
    const float* __restrict__ s2w, const int* __restrict__ adj,
    float ac0[4], float ac1[4]) {
    float (*att_t)[10] = (float (*)[10])smem;                 // 5120 B
    float* hbuf = (float*)(smem + 5120);                      // 65536 B
    const int i0 = s << 3;
    const int w = t >> 6, lane = t & 63;
    const char* hbytes = (const char*)(hw + (size_t)b * 32768);
    const int ph = s & 3;
    {
        char* lb = (char*)hbuf;
        const char* g = hbytes + ph * 32768;
        #pragma unroll
        for (int i = 0; i < 8; ++i)
            async16(g + i * 4096 + t * 16, lb + i * 4096 + t * 16);
    }
    {
        int cc0 = lane, cc1 = lane + 64;
        int ir0 = i0 + 2 * w, ir1 = ir0 + 1;
        const int* a0 = adj + (size_t)(b * 128 + ir0) * 128;
        const int* a1 = adj + (size_t)(b * 128 + ir1) * 128;
        int m00 = a0[cc0], m01 = a0[cc1], m10 = a1[cc0], m11 = a1[cc1];
        float sv0 = s1w[b * 128 + ir0], sv1 = s1w[b * 128 + ir1];
        float t0 = s2w[b * 128 + cc0],  t1 = s2w[b * 128 + cc1];
        float e00 = sv0 + t0; e00 = (e00 >= 0.f) ? e00 : 0.2f * e00;
        float e01 = sv0 + t1; e01 = (e01 >= 0.f) ? e01 : 0.2f * e01;
        float e10 = sv1 + t0; e10 = (e10 >= 0.f) ? e10 : 0.2f * e10;
        float e11 = sv1 + t1; e11 = (e11 >= 0.f) ? e11 : 0.2f * e11;
        float v00 = (m00 > 0) ? e00 : NEG_INF;
        float v01 = (m01 > 0) ? e01 : NEG_INF;
        float v10 = (m10 > 0) ? e10 : NEG_INF;
        float v11 = (m11 > 0) ? e11 : NEG_INF;
        float mx0 = fmaxf(v00, v01), mx1 = fmaxf(v10, v11);
        #pragma unroll
        for (int off = 1; off < 64; off <<= 1) {
            mx0 = fmaxf(mx0, __shfl_xor(mx0, off, 64));
            mx1 = fmaxf(mx1, __shfl_xor(mx1, off, 64));
        }
        float p00 = __expf(v00 - mx0), p01 = __expf(v01 - mx0);
        float p10 = __expf(v10 - mx1), p11 = __expf(v11 - mx1);
        float sm0 = p00 + p01, sm1 = p10 + p11;
        #pragma unroll
        for (int off = 1; off < 64; off <<= 1) {
            sm0 += __shfl_xor(sm0, off, 64);
            sm1 += __shfl_xor(sm1, off, 64);
        }
        float inv0 = 1.0f / sm0, inv1 = 1.0f / sm1;
        att_t[cc0][2 * w]     = p00 * inv0;
        att_t[cc1][2 * w]     = p01 * inv0;
        att_t[cc0][2 * w + 1] = p10 * inv1;
        att_t[cc1][2 * w + 1] = p11 * inv1;
    }
    __syncthreads();
    int tx = t & 63, ty = t >> 6;
    #pragma unroll
    for (int j = 0; j < 4; ++j) { ac0[j] = 0.f; ac1[j] = 0.f; }
    for (int c = 0; c < 4; ++c) {
        if (c < 3) {
            char* lb = (char*)hbuf + ((c + 1) & 1) * 32768;
            const char* g = hbytes + (((c + 1 + ph) & 3) * 32768);
            #pragma unroll
            for (int i = 0; i < 8; ++i)
                async16(g + i * 4096 + t * 16, lb + i * 4096 + t * 16);
        }
        const float* hc = hbuf + (c & 1) * 8192;
        const int jb = ((c + ph) & 3) * 32;
        #pragma unroll 4
        for (int jj = 0; jj < 32; ++jj) {
            float4 hv = *(const float4*)&hc[jj * 256 + 4 * tx];
            float2 ap = *(const float2*)&att_t[jb + jj][2 * ty];
            ac0[0] += ap.x * hv.x; ac0[1] += ap.x * hv.y;
            ac0[2] += ap.x * hv.z; ac0[3] += ap.x * hv.w;
            ac1[0] += ap.y * hv.x; ac1[1] += ap.y * hv.y;
            ac1[2] += ap.y * hv.z; ac1[3] += ap.y * hv.w;
        }
        __syncthreads();
    }
}

// ===========================================================================
// K1: gat layer 0 (nf@Wn+b projection prologue, proven) -> h0, s1_0, s2_0
// ===========================================================================
__global__ __launch_bounds__(256) void k_gat_first(
    const void* __restrict__ nf, const void* __restrict__ Wn_raw,
    const void* __restrict__ bn,
    const void* __restrict__ gat_W, const void* __restrict__ gat_a,
    float* __restrict__ hw, float* __restrict__ s1w, float* __restrict__ s2w) {
    __shared__ __align__(16) char smem[43008];
    const int t = threadIdx.x;
    const int row0 = blockIdx.x * 8;
    const int tx = t & 63, w = t >> 6;
    const int c0 = 4 * tx;
    float* xsT = (float*)smem;
    float acc0[4], acc1[4];

    if (sniff(Wn_raw)) {
        u16* Wb0 = (u16*)(smem + 10240);
        const u16* Wl = (const u16*)gat_W;   // layer 0
        auto stage = [&](const u16* src, int r0, int nr, int buf) {
            const char* g = (const char*)src + (size_t)r0 * 512;
            char* lp = (char*)(Wb0 + buf * 8192);
            int bytes = nr * 512;
            for (int off = t * 16; off < bytes; off += 4096)
                async16(g + off, lp + off);
        };
        auto tile = [&](int buf, int k0, int nr) {
            const u16* Wp = Wb0 + buf * 8192;
            #pragma unroll 8
            for (int kk = 0; kk < nr; ++kk) {
                uint2 wv = *(const uint2*)(Wp + kk * 256 + c0);
                float w0 = __uint_as_float(wv.x << 16);
                float w1 = __uint_as_float(wv.x & 0xffff0000u);
                float w2 = __uint_as_float(wv.y << 16);
                float w3 = __uint_as_float(wv.y & 0xffff0000u);
                float2 xp = *(const float2*)&xsT[(k0 + kk) * 10 + 2 * w];
                acc0[0] += xp.x * w0; acc0[1] += xp.x * w1;
                acc0[2] += xp.x * w2; acc0[3] += xp.x * w3;
                acc1[0] += xp.y * w0; acc1[1] += xp.y * w1;
                acc1[2] += xp.y * w2; acc1[3] += xp.y * w3;
            }
        };
        const u16* Wnl = (const u16*)Wn_raw;
        stage(Wnl, 0, 32, 0);
        const u16* nfu = (const u16*)nf;
        for (int i = t; i < 624; i += 256) {
            int r = i / 78, k = i - r * 78;
            xsT[k * 10 + r] = __uint_as_float(((unsigned)nfu[(row0 + r) * 78 + k]) << 16);
        }
        const __hip_bfloat16* bnb = (const __hip_bfloat16*)bn;
        #pragma unroll
        for (int j = 0; j < 4; ++j) { acc0[j] = b2f(bnb[c0 + j]); acc1[j] = acc0[j]; }
        __syncthreads();
        stage(Wnl, 32, 32, 1);
        tile(0, 0, 32);
        __syncthreads();
        stage(Wnl, 64, 14, 0);
        tile(1, 32, 32);
        __syncthreads();
        stage(Wl, 0, 32, 1);      // first main-W tile under last Wn tile
        tile(0, 64, 14);
        __syncthreads();
        #pragma unroll
        for (int j = 0; j < 4; ++j) {
            xsT[(c0 + j) * 10 + 2 * w]     = acc0[j];
            xsT[(c0 + j) * 10 + 2 * w + 1] = acc1[j];
        }
        __syncthreads();          // xsT ready; Wl tile0 drained, in buf1
        gat_core<1>(smem, t, row0, /*pb0=*/1, gat_W, gat_a, 0, hw, s1w, s2w);
    } else {
        const float* nff = (const float*)nf;
        for (int i = t; i < 624; i += 256) {
            int r = i / 78, k = i - r * 78;
            xsT[k * 10 + r] = nff[(row0 + r) * 78 + k];
        }
        __syncthreads();
        const float* Wnf = (const float*)Wn_raw;
        const float* bnf = (const float*)bn;
        #pragma unroll
        for (int j = 0; j < 4; ++j) { acc0[j] = bnf[c0 + j]; acc1[j] = acc0[j]; }
        for (int k = 0; k < 78; ++k) {
            float4 wf = *(const float4*)(Wnf + k * 256 + c0);
            float2 xp = *(const float2*)&xsT[k * 10 + 2 * w];
            acc0[0] += xp.x * wf.x; acc0[1] += xp.x * wf.y;
            acc0[2] += xp.x * wf.z; acc0[3] += xp.x * wf.w;
            acc1[0] += xp.y * wf.x; acc1[1] += xp.y * wf.y;
            acc1[2] += xp.y * wf.z; acc1[3] += xp.y * wf.w;
        }
        __syncthreads();
        #pragma unroll
        for (int j = 0; j < 4; ++j) {
            xsT[(c0 + j) * 10 + 2 * w]     = acc0[j];
            xsT[(c0 + j) * 10 + 2 * w + 1] = acc1[j];
        }
        __syncthreads();
        gat_core<0>(smem, t, row0, 0, gat_W, gat_a, 0, hw, s1w, s2w);
    }
}

// ===========================================================================
// K2/K3: attn layer l-1 + gat layer l, fused block-locally. The attn output
// rows/cols of thread t are exactly the xsT entries gat needs (ty==w, same
// cols), so relu'd accumulators go straight from registers into the LDS
// transpose — no global x buffer, no extra staging pass, no cross-block sync.
// ===========================================================================
__global__ __launch_bounds__(256) void k_attn_gat(
    const float* __restrict__ h_in, const float* __restrict__ s1_in,
    const float* __restrict__ s2_in, const int* __restrict__ adj,
    const void* __restrict__ gat_W, const void* __restrict__ gat_a, int l,
    const void* __restrict__ Wn_raw,
    float* __restrict__ h_out, float* __restrict__ s1_out, float* __restrict__ s2_out) {
    __shared__ __align__(16) char smem[74752];
    const int t = threadIdx.x;
    const int blk = blockIdx.x;
    const int b = blk >> 4, s = blk & 15;
    const int row0 = blk * 8;
    const int isbf = sniff(Wn_raw);

    float ac0[4], ac1[4];
    attn_compute(smem, t, b, s, h_in, s1_in, s2_in, adj, ac0, ac1);
    // last __syncthreads() of attn_compute: LDS fully dead -> reuse for gat.
    const int tx = t & 63, ty = t >> 6;
    const int c0 = 4 * tx;
    float* xsT = (float*)smem;
    if (isbf) {
        // issue W tile0 staging first so it drains at the barrier below
        u16* Wb0 = (u16*)(smem + 10240);
        const u16* Wl = (const u16*)gat_W + (size_t)l * 65536;
        for (int off = t * 16; off < 16384; off += 4096)
            async16((const char*)Wl + off, (char*)Wb0 + off);
    }
    #pragma unroll
    for (int j = 0; j < 4; ++j) {
        xsT[(c0 + j) * 10 + 2 * ty]     = fmaxf(ac0[j], 0.f);
        xsT[(c0 + j) * 10 + 2 * ty + 1] = fmaxf(ac1[j], 0.f);
    }
    __syncthreads();   // xsT visible + (bf16) W tile0 drained into buf0
    if (isbf)
        gat_core<1>(smem, t, row0, /*pb0=*/0, gat_W, gat_a, l, h_out, s1_out, s2_out);
    else
        gat_core<0>(smem, t, row0, 0, gat_W, gat_a, l, h_out, s1_out, s2_out);
}

// ===========================================================================
// K4: attn layer 2 + mean-pool partials (proven epilogue)
// ===========================================================================
__global__ __launch_bounds__(256) void k_attn_pool(
    const float* __restrict__ h_in, const float* __restrict__ s1_in,
    const float* __restrict__ s2_in, const int* __restrict__ adj,
    float* __restrict__ gpart) {
    __shared__ __align__(16) char smem[74752];
    const int t = threadIdx.x;
    const int blk = blockIdx.x;
    const int b = blk >> 4, s = blk & 15;
    float ac0[4], ac1[4];
    attn_compute(smem, t, b, s, h_in, s1_in, s2_in, adj, ac0, ac1);
    float (*pool_red)[256] = (float (*)[256])(smem + 70656);
    const int tx = t & 63, ty = t >> 6;
    float4 pr = {(fmaxf(ac0[0],0.f) + fmaxf(ac1[0],0.f)) * (1.f/128.f),
                 (fmaxf(ac0[1],0.f) + fmaxf(ac1[1],0.f)) * (1.f/128.f),
                 (fmaxf(ac0[2],0.f) + fmaxf(ac1[2],0.f)) * (1.f/128.f),
                 (fmaxf(ac0[3],0.f) + fmaxf(ac1[3],0.f)) * (1.f/128.f)};
    *(float4*)&pool_red[ty][4 * tx] = pr;
    __syncthreads();
    if (t < 64) {
        float4 r0 = ((const float4*)&pool_red[0][0])[t];
        float4 r1 = ((const float4*)&pool_red[1][0])[t];
        float4 r2 = ((const float4*)&pool_red[2][0])[t];
        float4 r3 = ((const float4*)&pool_red[3][0])[t];
        float4 o = {r0.x+r1.x+r2.x+r3.x, r0.y+r1.y+r2.y+r3.y,
                    r0.z+r1.z+r2.z+r3.z, r0.w+r1.w+r2.w+r3.w};
        *(float4*)&gpart[((size_t)b * 16 + s) * 256 + 4 * t] = o;
    }
}

// ===========================================================================
// K5: head — pool MLPs + concat + out MLP (round-1 proven body)
// ===========================================================================
template <typename T>
__device__ __forceinline__ void head_body(
    int b, int t, const float* __restrict__ gpart,
    const T* scaf, const T* W_sc, const T* b_sc,
    const T* gp_w1, const T* gp_b1, const T* gp_w2, const T* gp_b2,
    const T* out_w1, const T* out_b1, const T* out_w2, const T* out_b2,
    float* gin_s, float* sproj, float* scaf_s,
    float* red1, float* red2, float* z1g, float* z1s,
    float* cvec, float* hdn, float* outv) {
    float g = 0.f;
    #pragma unroll
    for (int gg = 0; gg < 16; ++gg) g += gpart[((size_t)b * 16 + gg) * 256 + t];
    gin_s[t] = g;
    if (t < 20) scaf_s[t] = ldv(scaf, b * 20 + t);
    __syncthreads();
    {
        float sa = ldv(b_sc, t);
        #pragma unroll
        for (int k = 0; k < 20; ++k) sa += scaf_s[k] * ldv(W_sc, k * 256 + t);
        sproj[t] = sa;
    }
    __syncthreads();
    {
        int j = t & 127, khalf = t >> 7;
        int k0 = khalf * 128;
        float a1 = 0.f, a2 = 0.f;
        #pragma unroll 16
        for (int kk = 0; kk < 128; ++kk) {
            int k = k0 + kk;
            float wv = ldv(gp_w1, k * 128 + j);
            a1 += gin_s[k] * wv;
            a2 += sproj[k] * wv;
        }
        red1[t] = a1; red2[t] = a2;
    }
    __syncthreads();
    if (t < 128) {
        float bb = ldv(gp_b1, t);
        z1g[t] = fmaxf(bb + red1[t] + red1[t + 128], 0.f);
        z1s[t] = fmaxf(bb + red2[t] + red2[t + 128], 0.f);
    }
    __syncthreads();
    {
        int j = t & 63, q = t >> 6;
        int k0 = q * 32;
        float a1 = 0.f, a2 = 0.f;
        #pragma unroll
        for (int kk = 0; kk < 32; ++kk) {
            int k = k0 + kk;
            float wv = ldv(gp_w2, k * 64 + j);
            a1 += z1g[k] * wv;
            a2 += z1s[k] * wv;
        }
        red1[t] = a1; red2[t] = a2;
    }
    __syncthreads();
    if (t < 64) {
        float bb = ldv(gp_b2, t);
        cvec[t]      = fmaxf(bb + red1[t] + red1[t + 64] + red1[t + 128] + red1[t + 192], 0.f);
        cvec[64 + t] = fmaxf(bb + red2[t] + red2[t + 64] + red2[t + 128] + red2[t + 192], 0.f);
    }
    __syncthreads();
    {
        int j = t & 127, khalf = t >> 7;
        int k0 = khalf * 64;
        float a = 0.f;
        #pragma unroll 16
        for (int kk = 0; kk < 64; ++kk) {
            int k = k0 + kk;
            a += cvec[k] * ldv(out_w1, k * 128 + j);
        }
        red1[t] = a;
    }
    __syncthreads();
    if (t < 128) hdn[t] = fmaxf(ldv(out_b1, t) + red1[t] + red1[t + 128], 0.f);
    __syncthreads();
    if (t < 13) {
        float a = ldv(out_b2, t);
        #pragma unroll 16
        for (int k = 0; k < 128; ++k) a += hdn[k] * ldv(out_w2, k * 13 + t);
        outv[t] = a;
    }
}

__global__ __launch_bounds__(256) void k_head(
    const float* __restrict__ gpart, const void* __restrict__ scaf,
    const void* __restrict__ W_sc, const void* __restrict__ b_sc,
    const void* __restrict__ gp_w1, const void* __restrict__ gp_b1,
    const void* __restrict__ gp_w2, const void* __restrict__ gp_b2,
    const void* __restrict__ out_w1, const void* __restrict__ out_b1,
    const void* __restrict__ out_w2, const void* __restrict__ out_b2,
    void* __restrict__ out, const void* __restrict__ Wn) {
    int isbf = sniff(Wn);
    int b = blockIdx.x;
    int t = threadIdx.x;
    __shared__ float gin_s[256], sproj[256], scaf_s[20];
    __shared__ float red1[256], red2[256];
    __shared__ float z1g[128], z1s[128], cvec[128], hdn[128], outv[13];
    if (isbf) {
        head_body<__hip_bfloat16>(b, t, gpart,
            (const __hip_bfloat16*)scaf, (const __hip_bfloat16*)W_sc, (const __hip_bfloat16*)b_sc,
            (const __hip_bfloat16*)gp_w1, (const __hip_bfloat16*)gp_b1,
            (const __hip_bfloat16*)gp_w2, (const __hip_bfloat16*)gp_b2,
            (const __hip_bfloat16*)out_w1, (const __hip_bfloat16*)out_b1,
            (const __hip_bfloat16*)out_w2, (const __hip_bfloat16*)out_b2,
            gin_s, sproj, scaf_s, red1, red2, z1g, z1s, cvec, hdn, outv);
    } else {
        head_body<float>(b, t, gpart,
            (const float*)scaf, (const float*)W_sc, (const float*)b_sc,
            (const float*)gp_w1, (const float*)gp_b1,
            (const float*)gp_w2, (const float*)gp_b2,
            (const float*)out_w1, (const float*)out_b1,
            (const float*)out_w2, (const float*)out_b2,
            gin_s, sproj, scaf_s, red1, red2, z1g, z1s, cvec, hdn, outv);
    }
    __syncthreads();
    if (t < 13) {
        if (isbf) ((__hip_bfloat16*)out)[b * 13 + t] = __float2bfloat16(outv[t]);
        else      ((float*)out)[b * 13 + t] = outv[t];
    }
}

extern "C" void kernel_launch(void* const* d_in, const int* in_sizes, int n_in,
                              void* d_out, int out_size, void* d_ws, size_t ws_size,
                              hipStream_t stream) {
    (void)in_sizes; (void)n_in; (void)out_size; (void)ws_size;
    const void* nf     = d_in[0];
    const int*  adj    = (const int*)d_in[2];
    const void* scaf   = d_in[3];
    const void* W_node = d_in[4];
    const void* b_node = d_in[5];
    const void* gat_W  = d_in[6];
    const void* gat_a  = d_in[7];
    const void* W_sc   = d_in[8];
    const void* b_sc   = d_in[9];
    const void* gp_w1  = d_in[10];
    const void* gp_b1  = d_in[11];
    const void* gp_w2  = d_in[12];
    const void* gp_b2  = d_in[13];
    const void* out_w1 = d_in[14];
    const void* out_b1 = d_in[15];
    const void* out_w2 = d_in[16];
    const void* out_b2 = d_in[17];

    float* ws    = (float*)d_ws;
    float* hA    = ws;                      // 1,048,576 f32
    float* hB    = ws + 1048576;            // 1,048,576 f32
    float* s1A   = ws + 2097152;            // 4096
    float* s2A   = ws + 2101248;            // 4096
    float* s1B   = ws + 2105344;            // 4096
    float* s2B   = ws + 2109440;            // 4096
    float* gpart = ws + 2113536;            // 131,072

    // K1: gat layer 0
    k_gat_first<<<512, 256, 0, stream>>>(nf, W_node, b_node, gat_W, gat_a,
                                         hA, s1A, s2A);
    // K2: attn0 + gat1 (block-local x handoff)
    k_attn_gat<<<512, 256, 0, stream>>>(hA, s1A, s2A, adj, gat_W, gat_a, 1,
                                        W_node, hB, s1B, s2B);
    // K3: attn1 + gat2
    k_attn_gat<<<512, 256, 0, stream>>>(hB, s1B, s2B, adj, gat_W, gat_a, 2,
                                        W_node, hA, s1A, s2A);
    // K4: attn2 + pool
    k_attn_pool<<<512, 256, 0, stream>>>(hA, s1A, s2A, adj, gpart);
    // K5: head
    k_head<<<32, 256, 0, stream>>>(gpart, scaf, W_sc, b_sc, gp_w1, gp_b1, gp_w2, gp_b2,
                                   out_w1, out_b1, out_w2, out_b2, d_out, W_node);
}